// Round 1
// baseline (1075.497 us; speedup 1.0000x reference)
//
#include <hip/hip_runtime.h>
#include <math.h>

#define N_NODES   100000
#define N_EDGES   1600000
#define N_GRAPHS  512
#define FEAT      128
#define EXTRA     8

#define SCHUNK 512
#define SNBLK ((N_NODES + SCHUNK - 1) / SCHUNK)   // 196

static __device__ __forceinline__ float selu_f(float x){
    const float alpha = 1.6732632423543772f;
    const float scale = 1.0507009873554805f;
    return scale * (x > 0.0f ? x : alpha * expm1f(x));
}

__global__ void k_zero_i4(int4* __restrict__ p, int n4){
    int i = blockIdx.x*blockDim.x + threadIdx.x;
    if (i < n4) p[i] = make_int4(0,0,0,0);
}

__global__ void k_count(const int* __restrict__ esrc, const int* __restrict__ edst,
                        int* __restrict__ cs, int* __restrict__ cd){
    int e = blockIdx.x*blockDim.x + threadIdx.x;
    if (e < N_EDGES){
        atomicAdd(&cs[esrc[e]], 1);
        atomicAdd(&cd[edst[e]], 1);
    }
}

__global__ void k_norms(const int* __restrict__ cs, const int* __restrict__ cd,
                        float* __restrict__ ns, float* __restrict__ nd){
    int i = blockIdx.x*blockDim.x + threadIdx.x;
    if (i < N_NODES){
        ns[i] = rsqrtf((float)(cs[i] > 1 ? cs[i] : 1));
        nd[i] = rsqrtf((float)(cd[i] > 1 ? cd[i] : 1));
    }
}

__global__ void k_scan1(const int* __restrict__ cnt, int* __restrict__ bsum){
    __shared__ int red[256];
    int b = blockIdx.x, t = threadIdx.x;
    int i0 = b*SCHUNK + t;
    int i1 = i0 + 256;
    int v = 0;
    if (i0 < N_NODES) v += cnt[i0];
    if (i1 < N_NODES) v += cnt[i1];
    red[t] = v; __syncthreads();
    for (int s = 128; s > 0; s >>= 1){
        if (t < s) red[t] += red[t+s];
        __syncthreads();
    }
    if (t == 0) bsum[b] = red[0];
}

__global__ void k_scan2(const int* __restrict__ bsum, int* __restrict__ boff,
                        int* __restrict__ row_ptr){
    if (threadIdx.x == 0 && blockIdx.x == 0){
        int run = 0;
        for (int i = 0; i < SNBLK; ++i){ boff[i] = run; run += bsum[i]; }
        row_ptr[N_NODES] = N_EDGES;
    }
}

__global__ void k_scan3(const int* __restrict__ cnt, const int* __restrict__ boff,
                        int* __restrict__ row_ptr, int* __restrict__ cursor){
    __shared__ int sc[256];
    int b = blockIdx.x, t = threadIdx.x;
    int base = b*SCHUNK;
    int e0 = base + 2*t, e1 = e0 + 1;
    int a0 = (e0 < N_NODES) ? cnt[e0] : 0;
    int a1 = (e1 < N_NODES) ? cnt[e1] : 0;
    int s = a0 + a1;
    sc[t] = s; __syncthreads();
    for (int d = 1; d < 256; d <<= 1){
        int v = (t >= d) ? sc[t-d] : 0;
        __syncthreads();
        sc[t] += v;
        __syncthreads();
    }
    int excl = sc[t] - s + boff[b];
    if (e0 < N_NODES){ row_ptr[e0] = excl;      cursor[e0] = excl; }
    if (e1 < N_NODES){ row_ptr[e1] = excl + a0; cursor[e1] = excl + a0; }
}

__global__ void k_scatter(const int* __restrict__ esrc, const int* __restrict__ edst,
                          int* __restrict__ cursor, int* __restrict__ col){
    int e = blockIdx.x*blockDim.x + threadIdx.x;
    if (e < N_EDGES){
        int d = edst[e];
        int p = atomicAdd(&cursor[d], 1);
        col[p] = esrc[e];
    }
}

// one wave (64 lanes) per node, 2 feats per lane
__global__ __launch_bounds__(256) void k_aggregate(
        const float* __restrict__ x, const int* __restrict__ row_ptr,
        const int* __restrict__ col, const float* __restrict__ ns,
        const float* __restrict__ nd, float* __restrict__ out){
    int gid  = blockIdx.x*blockDim.x + threadIdx.x;
    int node = gid >> 6;
    int lane = gid & 63;
    if (node >= N_NODES) return;
    int beg = row_ptr[node], end = row_ptr[node+1];
    const float2* __restrict__ x2 = (const float2*)x;
    float ax = 0.f, ay = 0.f;
    for (int e = beg; e < end; ++e){
        int s = col[e];
        float w = ns[s];
        float2 v = x2[(size_t)s*64 + lane];
        ax = fmaf(w, v.x, ax);
        ay = fmaf(w, v.y, ay);
    }
    float wd = nd[node];
    ((float2*)out)[(size_t)node*64 + lane] = make_float2(ax*wd, ay*wd);
}

// in-place row GEMM: x[32 rows] = act(x @ W + b); W staged in two 32KB halves
template<int ACT>
__global__ __launch_bounds__(256) void k_gemm(float* __restrict__ xb,
        const float* __restrict__ W, const float* __restrict__ bias){
    __shared__ float Wl[64*FEAT];   // 32 KB
    __shared__ float Xl[32*FEAT];   // 16 KB
    int t = threadIdx.x;
    size_t row0 = (size_t)blockIdx.x * 32;
    {
        const float4* src = (const float4*)(xb + row0*FEAT);
        float4* dst = (float4*)Xl;
        for (int i = t; i < 32*FEAT/4; i += 256) dst[i] = src[i];
    }
    int cb = (t & 31) * 4;
    int rb = (t >> 5) * 4;
    float acc[4][4] = {};
    for (int half = 0; half < 2; ++half){
        __syncthreads();
        {
            const float4* src = (const float4*)(W + half*64*FEAT);
            float4* dst = (float4*)Wl;
            for (int i = t; i < 64*FEAT/4; i += 256) dst[i] = src[i];
        }
        __syncthreads();
        for (int k = 0; k < 64; k += 4){
            float a[4][4], w[4][4];
            for (int r = 0; r < 4; ++r){
                float4 v = *(const float4*)&Xl[(rb+r)*FEAT + half*64 + k];
                a[r][0]=v.x; a[r][1]=v.y; a[r][2]=v.z; a[r][3]=v.w;
            }
            for (int kk = 0; kk < 4; ++kk){
                float4 v = *(const float4*)&Wl[(k+kk)*FEAT + cb];
                w[kk][0]=v.x; w[kk][1]=v.y; w[kk][2]=v.z; w[kk][3]=v.w;
            }
            for (int r = 0; r < 4; ++r)
                for (int c = 0; c < 4; ++c)
                    acc[r][c] += a[r][0]*w[0][c] + a[r][1]*w[1][c]
                               + a[r][2]*w[2][c] + a[r][3]*w[3][c];
        }
    }
    float4 bv = *(const float4*)&bias[cb];
    for (int r = 0; r < 4; ++r){
        float4 o;
        o.x = acc[r][0]+bv.x; o.y = acc[r][1]+bv.y;
        o.z = acc[r][2]+bv.z; o.w = acc[r][3]+bv.w;
        if (ACT){ o.x=selu_f(o.x); o.y=selu_f(o.y); o.z=selu_f(o.z); o.w=selu_f(o.w); }
        *(float4*)&xb[(row0 + rb + r)*FEAT + cb] = o;
    }
}

__global__ void k_goff(const int* __restrict__ gid, int* __restrict__ goff){
    int g = blockIdx.x*blockDim.x + threadIdx.x;
    if (g > N_GRAPHS) return;
    if (g == N_GRAPHS){ goff[g] = N_NODES; return; }
    int lo = 0, hi = N_NODES;
    while (lo < hi){
        int mid = (lo + hi) >> 1;
        if (gid[mid] < g) lo = mid + 1; else hi = mid;
    }
    goff[g] = lo;
}

// block per graph, 128 threads = feature columns; segment mean
__global__ void k_readout(const float* __restrict__ x, const int* __restrict__ goff,
                          float* __restrict__ emb){
    int g = blockIdx.x, f = threadIdx.x;
    int beg = goff[g], end = goff[g+1];
    float s = 0.f;
    for (int n = beg; n < end; ++n) s += x[(size_t)n*FEAT + f];
    int c = end - beg; if (c < 1) c = 1;
    emb[g*FEAT + f] = s / (float)c;
}

// block per graph: 136 -> 256 -> 128 -> 1 fused MLP head
__global__ __launch_bounds__(256) void k_mlp(
        const float* __restrict__ emb, const float* __restrict__ fg,
        const float* __restrict__ Wl1, const float* __restrict__ bl1,
        const float* __restrict__ Wl2, const float* __restrict__ bl2,
        const float* __restrict__ Wl3, const float* __restrict__ bl3,
        float* __restrict__ out){
    __shared__ float in136[FEAT+EXTRA];
    __shared__ float y1[256];
    __shared__ float y2[128];
    int g = blockIdx.x, t = threadIdx.x;
    if (t < FEAT)            in136[t] = emb[g*FEAT + t];
    else if (t < FEAT+EXTRA) in136[t] = fg[g*EXTRA + (t-FEAT)];
    __syncthreads();
    {
        float acc = bl1[t];
        for (int i = 0; i < FEAT+EXTRA; ++i) acc += in136[i] * Wl1[i*256 + t];
        y1[t] = selu_f(acc);
    }
    __syncthreads();
    if (t < 128){
        float acc = bl2[t];
        for (int i = 0; i < 256; ++i) acc += y1[i] * Wl2[i*128 + t];
        y2[t] = selu_f(acc);
    }
    __syncthreads();
    if (t == 0){
        float s = bl3[0];
        for (int i = 0; i < 128; ++i) s += y2[i] * Wl3[i];
        out[g] = s;
    }
}

extern "C" void kernel_launch(void* const* d_in, const int* in_sizes, int n_in,
                              void* d_out, int out_size, void* d_ws, size_t ws_size,
                              hipStream_t stream){
    const float* feats_node  = (const float*)d_in[0];
    const float* feats_graph = (const float*)d_in[1];
    const int*   edge_src    = (const int*)d_in[2];
    const int*   edge_dst    = (const int*)d_in[3];
    const int*   graph_ids   = (const int*)d_in[4];
    const float* W1 =(const float*)d_in[5];  const float* b1 =(const float*)d_in[6];
    const float* W2 =(const float*)d_in[7];  const float* b2 =(const float*)d_in[8];
    const float* W3 =(const float*)d_in[9];  const float* b3 =(const float*)d_in[10];
    const float* Wl1=(const float*)d_in[11]; const float* bl1=(const float*)d_in[12];
    const float* Wl2=(const float*)d_in[13]; const float* bl2=(const float*)d_in[14];
    const float* Wl3=(const float*)d_in[15]; const float* bl3=(const float*)d_in[16];
    float* out = (float*)d_out;
    (void)in_sizes; (void)n_in; (void)out_size; (void)ws_size;

    // workspace layout (~112 MB total)
    char* ws = (char*)d_ws;
    size_t off = 0;
    auto alloc = [&](size_t bytes)->void*{
        void* p = ws + off;
        off += (bytes + 255) & ~(size_t)255;
        return p;
    };
    float* bufA    = (float*)alloc((size_t)N_NODES*FEAT*4);
    float* bufB    = (float*)alloc((size_t)N_NODES*FEAT*4);
    float* ns      = (float*)alloc((size_t)N_NODES*4);
    float* nd      = (float*)alloc((size_t)N_NODES*4);
    int*   cnt     = (int*)  alloc((size_t)2*N_NODES*4);
    int*   cnt_src = cnt;
    int*   cnt_dst = cnt + N_NODES;
    int*   row_ptr = (int*)  alloc((size_t)(N_NODES+1)*4);
    int*   cursor  = (int*)  alloc((size_t)N_NODES*4);
    int*   col     = (int*)  alloc((size_t)N_EDGES*4);
    int*   bsum    = (int*)  alloc((size_t)SNBLK*4);
    int*   boff    = (int*)  alloc((size_t)SNBLK*4);
    int*   goff    = (int*)  alloc((size_t)(N_GRAPHS+1)*4);
    float* emb     = (float*)alloc((size_t)N_GRAPHS*FEAT*4);

    // degree counting + norms
    k_zero_i4<<<dim3((2*N_NODES/4 + 255)/256), dim3(256), 0, stream>>>((int4*)cnt, 2*N_NODES/4);
    k_count<<<dim3((N_EDGES+255)/256), dim3(256), 0, stream>>>(edge_src, edge_dst, cnt_src, cnt_dst);
    k_norms<<<dim3((N_NODES+255)/256), dim3(256), 0, stream>>>(cnt_src, cnt_dst, ns, nd);

    // CSR build (by dst)
    k_scan1<<<dim3(SNBLK), dim3(256), 0, stream>>>(cnt_dst, bsum);
    k_scan2<<<dim3(1), dim3(64), 0, stream>>>(bsum, boff, row_ptr);
    k_scan3<<<dim3(SNBLK), dim3(256), 0, stream>>>(cnt_dst, boff, row_ptr, cursor);
    k_scatter<<<dim3((N_EDGES+255)/256), dim3(256), 0, stream>>>(edge_src, edge_dst, cursor, col);

    // 3 GraphConv layers (aggregate then in-place GEMM+bias(+SELU))
    dim3 aggGrid((N_NODES*64 + 255)/256);
    k_aggregate<<<aggGrid, dim3(256), 0, stream>>>(feats_node, row_ptr, col, ns, nd, bufA);
    k_gemm<1><<<dim3(N_NODES/32), dim3(256), 0, stream>>>(bufA, W1, b1);
    k_aggregate<<<aggGrid, dim3(256), 0, stream>>>(bufA, row_ptr, col, ns, nd, bufB);
    k_gemm<1><<<dim3(N_NODES/32), dim3(256), 0, stream>>>(bufB, W2, b2);
    k_aggregate<<<aggGrid, dim3(256), 0, stream>>>(bufB, row_ptr, col, ns, nd, bufA);
    k_gemm<0><<<dim3(N_NODES/32), dim3(256), 0, stream>>>(bufA, W3, b3);

    // readout + MLP head
    k_goff<<<dim3((N_GRAPHS+1+255)/256), dim3(256), 0, stream>>>(graph_ids, goff);
    k_readout<<<dim3(N_GRAPHS), dim3(FEAT), 0, stream>>>(bufA, goff, emb);
    k_mlp<<<dim3(N_GRAPHS), dim3(256), 0, stream>>>(emb, feats_graph,
        Wl1, bl1, Wl2, bl2, Wl3, bl3, out);
}